// Round 7
// baseline (248.117 us; speedup 1.0000x reference)
//
#include <hip/hip_runtime.h>
#include <hip/hip_cooperative_groups.h>
#include <math.h>

namespace cg = cooperative_groups;

// Problem shape (fixed by harness setup_inputs): B=8, N=M=4096, D=3, fp32.
#define B_SZ 8
#define N_SZ 4096
#define M_SZ 4096
#define NQ (B_SZ * N_SZ)            // 32768 queries per direction
#define TOT (2 * NQ)                // 65536 total queries

#define THREADS 256
#define QPT 8                       // queries per thread (all scalar)
#define QPB (THREADS * QPT)         // 2048 queries per block
#define ITILES (N_SZ / QPB)         // 2
#define JTILE 256                   // targets staged in LDS per block
#define NJT (M_SZ / JTILE)          // 16 target tiles (= partials per query)
#define JPAIRS (JTILE / 2)          // 128 target pairs per tile

#define NBLK1 (ITILES * NJT * B_SZ * 2)  // 512 phase-1 blocks
#define NBLK2 (TOT / 256)                // 256 tail blocks (subset of the 512)

// ws layout (floats):
//   part[g * TOT + q] : g in [0,NJT) -> 4 MB
//   bsum[NBLK2]       : at offset NJT*TOT
// Every slot is written before it is read (ordered by grid.sync) -> no ws
// init needed, no atomics anywhere, deterministic summation order (same as
// the R4 3-kernel version -> absmax should stay 0).
//
// R0-R6 lesson: phase-1 compute is NOT the wall (2x FLOP reduction in
// R5/R6 made totals WORSE; ILP/TLP/occupancy/min3 all +-2us). Budget:
// fill ~41us + phase1 ~12-16us + tail ~2us + ~20-25us of per-dispatch
// overhead (4 serialized dispatches). This round attacks dispatch count:
// 3 kernels -> 1 cooperative kernel (fill + 1 dispatch total).

__device__ __forceinline__ float min3f(float a, float b, float c) {
    // fminf(fminf(a,b),c) does NOT auto-fuse to v_min3_f32 (R1); force it.
    float d;
    asm("v_min3_f32 %0, %1, %2, %3" : "=v"(d) : "v"(a), "v"(b), "v"(c));
    return d;
}

// grid: x = ITILES*NJT (32), y = B (8), z = dir (2) -> 512 blocks
// (256 threads, 4KB LDS, co-resident at 2 blocks/CU with headroom).
__global__ __launch_bounds__(THREADS)
void chamfer_fused_kernel(const float* __restrict__ pred,
                          const float* __restrict__ tgt,
                          float* __restrict__ part,
                          float* __restrict__ bsum,
                          float* __restrict__ out)
{
    const int b   = blockIdx.y;
    const int dir = blockIdx.z;
    const int tid = threadIdx.x;
    const int fb  = blockIdx.x + (ITILES * NJT) * (b + B_SZ * dir); // flat id

    // ---------------- Phase 1 (R4-proven structure, verbatim) ----------------
    const float* Q;
    const float* Db;
    int qoff;
    if (dir == 0) { Q = pred + (size_t)b * N_SZ * 3; Db = tgt  + (size_t)b * M_SZ * 3; qoff = b * N_SZ; }
    else          { Q = tgt  + (size_t)b * M_SZ * 3; Db = pred + (size_t)b * N_SZ * 3; qoff = NQ + b * M_SZ; }

    const int itile = blockIdx.x >> 4;          // / NJT
    const int g     = blockIdx.x & (NJT - 1);

    __shared__ float4 sp[JTILE];                // x,y,z,h  (h = |t|^2 / 2)
    {
        const float* s = Db + (size_t)(g * JTILE + tid) * 3;
        float x = s[0], y = s[1], z = s[2];
        sp[tid] = make_float4(x, y, z, 0.5f * (x * x + y * y + z * z));
    }
    __syncthreads();

    // 8 queries per thread, scalar negated coords; q^2/2 folded in at store.
    float qxn[QPT], qyn[QPT], qzn[QPT], q2h[QPT], mn[QPT];
    const int qbase = itile * QPB + tid;
#pragma unroll
    for (int i = 0; i < QPT; ++i) {
        const int qi = qbase + i * THREADS;
        float x = Q[qi * 3 + 0], y = Q[qi * 3 + 1], z = Q[qi * 3 + 2];
        qxn[i] = -x;
        qyn[i] = -y;
        qzn[i] = -z;
        q2h[i] = 0.5f * (x * x + y * y + z * z);
        mn[i]  = 3.0e38f;
    }

    // Per target-pair: 2 broadcast ds_read_b128; per query 6 fma + 1 min3.
#pragma unroll 4
    for (int jp = 0; jp < JPAIRS; ++jp) {
        float4 t0 = sp[2 * jp];
        float4 t1 = sp[2 * jp + 1];
#pragma unroll
        for (int i = 0; i < QPT; ++i) {
            float s0 = fmaf(qxn[i], t0.x, t0.w);
            s0 = fmaf(qyn[i], t0.y, s0);
            s0 = fmaf(qzn[i], t0.z, s0);
            float s1 = fmaf(qxn[i], t1.x, t1.w);
            s1 = fmaf(qyn[i], t1.y, s1);
            s1 = fmaf(qzn[i], t1.z, s1);
            mn[i] = min3f(mn[i], s0, s1);
        }
    }

    // Fold q^2/2 -> partial d^2/2; plain coalesced stores.
    {
        float* pg = part + (size_t)g * TOT + qoff;
#pragma unroll
        for (int i = 0; i < QPT; ++i)
            pg[qbase + i * THREADS] = mn[i] + q2h[i];
    }

    // ---------------- grid barrier #1 (part fully written) ----------------
    __threadfence();
    cg::this_grid().sync();

    // ---------------- Phase 2: first 256 blocks, 1 query/thread ----------------
    __shared__ float rs[4];
    if (fb < NBLK2) {
        const int q = fb * 256 + tid;
        float m = 3.0e38f;
#pragma unroll
        for (int gg = 0; gg < NJT; ++gg) m = fminf(m, part[(size_t)gg * TOT + q]);
        float d = sqrtf(2.0f * fmaxf(m, 0.0f));
#pragma unroll
        for (int off = 32; off > 0; off >>= 1) d += __shfl_down(d, off);
        if ((tid & 63) == 0) rs[tid >> 6] = d;
        __syncthreads();
        if (tid == 0) bsum[fb] = rs[0] + rs[1] + rs[2] + rs[3];
    }

    // ---------------- grid barrier #2 (bsum fully written) ----------------
    __threadfence();
    cg::this_grid().sync();

    // ---------------- Phase 3: block 0, one wave ----------------
    if (fb == 0 && tid < 64) {
        float s = bsum[tid] + bsum[tid + 64] + bsum[tid + 128] + bsum[tid + 192];
#pragma unroll
        for (int off = 32; off > 0; off >>= 1) s += __shfl_down(s, off);
        // loss = mean(min_p2t) + mean(min_t2p) = (sum of all NN dists)/NQ
        if (tid == 0) out[0] = s * (1.0f / (float)NQ);
    }
}

extern "C" void kernel_launch(void* const* d_in, const int* in_sizes, int n_in,
                              void* d_out, int out_size, void* d_ws, size_t ws_size,
                              hipStream_t stream) {
    const float* pred = (const float*)d_in[0];  // [B,N,3]
    const float* tgt  = (const float*)d_in[1];  // [B,M,3]
    float* out = (float*)d_out;

    float* part = (float*)d_ws;                 // NJT*TOT floats = 4 MB
    float* bsum = part + (size_t)NJT * TOT;     // NBLK2 floats

    dim3 grid1(ITILES * NJT, B_SZ, 2);          // 512 blocks, co-resident
    dim3 blk(THREADS, 1, 1);
    void* args[] = { (void*)&pred, (void*)&tgt, (void*)&part,
                     (void*)&bsum, (void*)&out };
    hipLaunchCooperativeKernel((const void*)chamfer_fused_kernel,
                               grid1, blk, args, 0, stream);
}

// Round 8
// 79.955 us; speedup vs baseline: 3.1032x; 3.1032x over previous
//
#include <hip/hip_runtime.h>
#include <math.h>

// Problem shape (fixed by harness setup_inputs): B=8, N=M=4096, D=3, fp32.
#define B_SZ 8
#define N_SZ 4096
#define M_SZ 4096
#define NQ (B_SZ * N_SZ)            // 32768 queries per direction
#define TOT (2 * NQ)                // 65536 total queries

#define THREADS 256
#define QPT 8                       // queries per thread (4 packed f32x2 slots)
#define SLOTS (QPT / 2)
#define QPB (THREADS * QPT)         // 2048 queries per block
#define ITILES (N_SZ / QPB)         // 2
#define JTILE 256                   // targets staged in LDS per block
#define NJT (M_SZ / JTILE)          // 16 target tiles (= partials per query)

#define NBLK2 (TOT / 256)           // 256 phase-2 blocks

typedef float f32x2 __attribute__((ext_vector_type(2)));

// Session conclusion (R0-R7 evidence): timed region = harness poison-fill
// (41 us @ 82% HBM peak, 256 MB workspace, outside kernel control) + ~22 us
// fixed dispatch/replay overhead + ~19 us of kernels, of which phase 1 runs
// at ~80% of its VALU issue floor (7 cyc per 2 point-pairs, wave64).
// Measured dead ends: FLOP-halving via symmetric tiles (R5/R6: WORSE -
// per-block overhead dominates), QPT/JTILE occupancy trades (R2/R3: nil),
// scalar+v_min3 loop (R4: nil), atomic tail fusion (R1-R3: nil),
// cooperative-kernel launch fusion (R7: grid.sync costs ~150 us on 512
// blocks - 3x regression). This file is the best-measured artifact (R0,
// 78.6 us), reverted verbatim.
//
// ws layout (floats):
//   part[g * TOT + q]  : g in [0,NJT), q in [0,TOT)   -> 4 MB
//   bsum[NBLK2]        : at offset NJT*TOT            -> 1 KB
// Every slot is written by phase 1 -> no ws init needed, no atomics.
//
// score(q,t) = t^2/2 - q.t ; after the tile loop we add q^2/2 -> d^2/2.
// grid: x = ITILES*NJT (32), y = B (8), z = dir (2)  -> 512 blocks.
__global__ __launch_bounds__(THREADS)
void chamfer_partial_kernel(const float* __restrict__ pred,
                            const float* __restrict__ tgt,
                            float* __restrict__ part)
{
    const int b   = blockIdx.y;
    const int dir = blockIdx.z;

    const float* Q;
    const float* Db;
    int qoff;
    if (dir == 0) { Q = pred + (size_t)b * N_SZ * 3; Db = tgt  + (size_t)b * M_SZ * 3; qoff = b * N_SZ; }
    else          { Q = tgt  + (size_t)b * M_SZ * 3; Db = pred + (size_t)b * N_SZ * 3; qoff = NQ + b * M_SZ; }

    const int itile = blockIdx.x >> 4;          // / NJT
    const int g     = blockIdx.x & (NJT - 1);

    __shared__ float4 sp[JTILE];                // x,y,z,h  (h = |t|^2 / 2)
    {
        const float* s = Db + (size_t)(g * JTILE + threadIdx.x) * 3;
        float x = s[0], y = s[1], z = s[2];
        sp[threadIdx.x] = make_float4(x, y, z, 0.5f * (x * x + y * y + z * z));
    }
    __syncthreads();

    // 8 queries per thread: negated coords packed 2-per-f32x2; q^2/2 kept
    // to fold in after the tile loop (so phase 2 never reads the points).
    f32x2 qxn[SLOTS], qyn[SLOTS], qzn[SLOTS], q2h[SLOTS], mn[SLOTS];
    const int qbase = itile * QPB + threadIdx.x;
#pragma unroll
    for (int s = 0; s < SLOTS; ++s) {
        const int i0 = qbase + (2 * s) * THREADS;
        const int i1 = qbase + (2 * s + 1) * THREADS;
        float x0 = Q[i0 * 3 + 0], y0 = Q[i0 * 3 + 1], z0 = Q[i0 * 3 + 2];
        float x1 = Q[i1 * 3 + 0], y1 = Q[i1 * 3 + 1], z1 = Q[i1 * 3 + 2];
        qxn[s] = { -x0, -x1 };
        qyn[s] = { -y0, -y1 };
        qzn[s] = { -z0, -z1 };
        q2h[s] = { 0.5f * (x0 * x0 + y0 * y0 + z0 * z0),
                   0.5f * (x1 * x1 + y1 * y1 + z1 * z1) };
        mn[s]  = { 3.0e38f, 3.0e38f };
    }

    // Inner loop: 1 broadcast ds_read_b128; per slot 3 pk_fma + 2 v_min_f32
    // -> ~2.5 VALU insts per point-pair.
#pragma unroll 8
    for (int j = 0; j < JTILE; ++j) {
        float4 t = sp[j];
        f32x2 tx = { t.x, t.x };
        f32x2 ty = { t.y, t.y };
        f32x2 tz = { t.z, t.z };
        f32x2 th = { t.w, t.w };
#pragma unroll
        for (int s = 0; s < SLOTS; ++s) {
            f32x2 sc = th + qxn[s] * tx;
            sc += qyn[s] * ty;
            sc += qzn[s] * tz;
            mn[s].x = fminf(mn[s].x, sc.x);
            mn[s].y = fminf(mn[s].y, sc.y);
        }
    }

    // Fold q^2/2 -> partial d^2/2; plain coalesced stores (no atomics).
    float* pg = part + (size_t)g * TOT + qoff;
#pragma unroll
    for (int s = 0; s < SLOTS; ++s) {
        f32x2 v = mn[s] + q2h[s];
        pg[qbase + (2 * s) * THREADS]     = v.x;
        pg[qbase + (2 * s + 1) * THREADS] = v.y;
    }
}

// Phase 2: one query per thread; 16 coalesced independent loads; block sum.
__global__ __launch_bounds__(256)
void chamfer_combine_kernel(const float* __restrict__ part,
                            float* __restrict__ bsum)
{
    const int q = blockIdx.x * 256 + threadIdx.x;
    float m = 3.0e38f;
#pragma unroll
    for (int g = 0; g < NJT; ++g) m = fminf(m, part[(size_t)g * TOT + q]);
    float d = sqrtf(2.0f * fmaxf(m, 0.0f));
#pragma unroll
    for (int off = 32; off > 0; off >>= 1) d += __shfl_down(d, off);
    __shared__ float r[4];
    if ((threadIdx.x & 63) == 0) r[threadIdx.x >> 6] = d;
    __syncthreads();
    if (threadIdx.x == 0) bsum[blockIdx.x] = r[0] + r[1] + r[2] + r[3];
}

// Phase 3: one wave sums the 256 block partials.
__global__ __launch_bounds__(64)
void chamfer_final_kernel(const float* __restrict__ bsum,
                          float* __restrict__ out)
{
    float s = 0.0f;
#pragma unroll
    for (int i = 0; i < NBLK2 / 64; ++i) s += bsum[threadIdx.x + i * 64];
#pragma unroll
    for (int off = 32; off > 0; off >>= 1) s += __shfl_down(s, off);
    // loss = mean(min_p2t) + mean(min_t2p) = (sum of all NN dists)/NQ  (N==M)
    if (threadIdx.x == 0) out[0] = s * (1.0f / (float)NQ);
}

extern "C" void kernel_launch(void* const* d_in, const int* in_sizes, int n_in,
                              void* d_out, int out_size, void* d_ws, size_t ws_size,
                              hipStream_t stream) {
    const float* pred = (const float*)d_in[0];  // [B,N,3]
    const float* tgt  = (const float*)d_in[1];  // [B,M,3]
    float* out = (float*)d_out;

    float* part = (float*)d_ws;                 // NJT*TOT floats = 4 MB
    float* bsum = part + (size_t)NJT * TOT;     // NBLK2 floats

    dim3 grid1(ITILES * NJT, B_SZ, 2);
    chamfer_partial_kernel<<<grid1, THREADS, 0, stream>>>(pred, tgt, part);
    chamfer_combine_kernel<<<NBLK2, 256, 0, stream>>>(part, bsum);
    chamfer_final_kernel<<<1, 64, 0, stream>>>(bsum, out);
}